// Round 12
// baseline (33.784 us; speedup 1.0000x reference)
//
#include <hip/hip_runtime.h>
#include <math.h>

// B=8, N=20, H=W=512. loss = sum(bce*valid)/cnt where the last point n with
// exp(-d2/(2*5^2)) > 0.1 (<=> d2 < 50*ln10) defines the per-pixel label.
// Single dispatch, 512 blocks x 256 (R9 worker body, best=19.56us).
// Completion: every block's wave 0 checks all 512 flags once (last-arriver
// fast path, no wakeup latency); block 0 sleep-polls as backstop. Both paths
// use IDENTICAL 64-lane summation order -> byte-identical duplicate writes.

#define R2_THRESH 115.12925464970229f
#define HW 512
#define NPTS 20
#define NBLOCKS 512
#define MAGIC 0x5F3C9A17u
#define MAGIC2 0x5F3C9A175F3C9A17ull

__device__ __forceinline__ void finalize64(const unsigned long long* slots,
                                           float* out, int t) {
    // lane t sums blocks 8t..8t+7 in fixed order; identical in both paths.
    float S = 0.0f, C = 0.0f;
    #pragma unroll
    for (int j = 0; j < 8; ++j) {
        unsigned long long w = __hip_atomic_load(&slots[8 * t + j],
                                                 __ATOMIC_RELAXED, __HIP_MEMORY_SCOPE_AGENT);
        S += __uint_as_float((unsigned)(w & 0xffffffffull));
        C += __uint_as_float((unsigned)(w >> 32));
    }
    #pragma unroll
    for (int off = 32; off > 0; off >>= 1) {
        S += __shfl_down(S, off, 64);
        C += __shfl_down(C, off, 64);
    }
    if (t == 0) out[0] = (C > 0.0f) ? (S / C) : 0.0f;
}

__global__ __launch_bounds__(256)
void pce_kernel(const float* __restrict__ y_pred,
                const int* __restrict__ point_labels,
                const float* __restrict__ point_coords,
                unsigned long long* __restrict__ slots, // [512] packed {C:hi32,S:lo32}
                unsigned* __restrict__ flags,           // [512]; != MAGIC on entry, cleared on exit
                float* __restrict__ out) {
    const int bid  = blockIdx.x;
    const int b    = bid >> 6;
    const int y0   = (bid & 63) * 8;
    const int tid  = threadIdx.x;
    const int r    = tid >> 5;               // 8 rows, 32 lanes each
    const int lane = tid & 31;

    __shared__ float s_strip[8][HW];         // 16 KB
    __shared__ float s_xc[8][NPTS], s_lim[8][NPTS], s_lab[8][NPTS];

    // ---- issue strip loads first (independent of coords) ----
    const float4* grow = (const float4*)(y_pred + (size_t)b * HW * HW + (size_t)(y0 + r) * HW);
    float4 v0 = grow[lane];
    float4 v1 = grow[lane + 32];
    float4 v2 = grow[lane + 64];
    float4 v3 = grow[lane + 96];

    // ---- coords / tables / bbox (overlaps strip loads) ----
    float xlo = INFINITY, xhi = -INFINITY;
    if (lane < NPTS) {
        float2 cc = ((const float2*)point_coords)[b * NPTS + lane];
        float yc  = cc.x * (float)HW;
        float xc  = cc.y * (float)HW;
        float dy  = (float)(y0 + r) - yc;
        float lim = R2_THRESH - dy * dy;      // lim<=0 -> dx*dx<lim never true
        s_xc[r][lane]  = xc;
        s_lim[r][lane] = lim;
        s_lab[r][lane] = (float)point_labels[b * NPTS + lane];
        if (lim > 0.0f) {
            float s = sqrtf(lim);
            xlo = xc - s;
            xhi = xc + s;
        }
    }
    #pragma unroll
    for (int off = 16; off > 0; off >>= 1) {
        xlo = fminf(xlo, __shfl_xor(xlo, off, 32));
        xhi = fmaxf(xhi, __shfl_xor(xhi, off, 32));
    }
    const int x0 = (int)fminf(fmaxf(floorf(xlo), 0.0f), 512.0f);
    const int x1 = (int)fminf(fmaxf(ceilf(xhi), -1.0f), 511.0f);   // empty -> x0 > x1

    // ---- strip -> LDS ----
    {
        float4* dst = (float4*)&s_strip[r][0];
        dst[lane]      = v0;
        dst[lane + 32] = v1;
        dst[lane + 64] = v2;
        dst[lane + 96] = v3;
    }
    __syncthreads();

    // ---- pixel loop over this row's bbox (LDS reads) ----
    float sum = 0.0f, cnt = 0.0f;
    for (int px = x0 + lane; px <= x1; px += 32) {
        float l = s_strip[r][px];
        const float fx = (float)px;
        float lab = 0.0f;
        bool  valid = false;
        #pragma unroll
        for (int k = 0; k < NPTS; ++k) {
            float dx = fx - s_xc[r][k];
            if (dx * dx < s_lim[r][k]) { lab = s_lab[r][k]; valid = true; }  // last k wins
        }
        if (valid) {
            sum += fmaxf(l, 0.0f) - l * lab + log1pf(expf(-fabsf(l)));
            cnt += 1.0f;
        }
    }

    // ---- block reduction ----
    #pragma unroll
    for (int off = 32; off > 0; off >>= 1) {
        sum += __shfl_down(sum, off, 64);
        cnt += __shfl_down(cnt, off, 64);
    }
    __shared__ float rs[4], rc[4];
    if ((tid & 63) == 0) { rs[tid >> 6] = sum; rc[tid >> 6] = cnt; }
    __syncthreads();
    if (tid == 0) {
        float S = rs[0] + rs[1] + rs[2] + rs[3];
        float C = rc[0] + rc[1] + rc[2] + rc[3];
        unsigned long long w = ((unsigned long long)__float_as_uint(C) << 32)
                             | (unsigned long long)__float_as_uint(S);
        __hip_atomic_store(&slots[bid], w, __ATOMIC_RELAXED, __HIP_MEMORY_SCOPE_AGENT);
        __hip_atomic_store(&flags[bid], MAGIC, __ATOMIC_RELEASE, __HIP_MEMORY_SCOPE_AGENT);
    }
    if (tid >= 64) return;

    const unsigned long long* fq = (const unsigned long long*)flags;  // lane t: ull 4t..4t+3

    if (bid != 0) {
        // ---- last-arriver fast path: one-shot check of all 512 flags ----
        unsigned long long a0 = __hip_atomic_load(&fq[4 * tid + 0], __ATOMIC_ACQUIRE, __HIP_MEMORY_SCOPE_AGENT);
        unsigned long long a1 = __hip_atomic_load(&fq[4 * tid + 1], __ATOMIC_ACQUIRE, __HIP_MEMORY_SCOPE_AGENT);
        unsigned long long a2 = __hip_atomic_load(&fq[4 * tid + 2], __ATOMIC_ACQUIRE, __HIP_MEMORY_SCOPE_AGENT);
        unsigned long long a3 = __hip_atomic_load(&fq[4 * tid + 3], __ATOMIC_ACQUIRE, __HIP_MEMORY_SCOPE_AGENT);
        int ok = (a0 == MAGIC2) && (a1 == MAGIC2) && (a2 == MAGIC2) && (a3 == MAGIC2);
        if (!__all(ok)) return;               // not complete yet -> backstop handles it
        finalize64(slots, out, tid);          // duplicate write is byte-identical
        return;                               // do NOT clear (block 0 owns cleanup)
    }

    // ---- block 0 backstop: sleep-backed poll until all 512 set ----
    {
        unsigned long long a0 = 0, a1 = 0, a2 = 0, a3 = 0;
        for (;;) {
            if (a0 != MAGIC2) a0 = __hip_atomic_load(&fq[4 * tid + 0], __ATOMIC_ACQUIRE, __HIP_MEMORY_SCOPE_AGENT);
            if (a1 != MAGIC2) a1 = __hip_atomic_load(&fq[4 * tid + 1], __ATOMIC_ACQUIRE, __HIP_MEMORY_SCOPE_AGENT);
            if (a2 != MAGIC2) a2 = __hip_atomic_load(&fq[4 * tid + 2], __ATOMIC_ACQUIRE, __HIP_MEMORY_SCOPE_AGENT);
            if (a3 != MAGIC2) a3 = __hip_atomic_load(&fq[4 * tid + 3], __ATOMIC_ACQUIRE, __HIP_MEMORY_SCOPE_AGENT);
            if (a0 == MAGIC2 && a1 == MAGIC2 && a2 == MAGIC2 && a3 == MAGIC2) break;
            __builtin_amdgcn_s_sleep(1);
        }
    }
    finalize64(slots, out, tid);
    // ---- clear all flags for next replay (my slot reads are done) ----
    unsigned long long* fw = (unsigned long long*)flags;
    __hip_atomic_store(&fw[4 * tid + 0], 0ull, __ATOMIC_RELAXED, __HIP_MEMORY_SCOPE_AGENT);
    __hip_atomic_store(&fw[4 * tid + 1], 0ull, __ATOMIC_RELAXED, __HIP_MEMORY_SCOPE_AGENT);
    __hip_atomic_store(&fw[4 * tid + 2], 0ull, __ATOMIC_RELAXED, __HIP_MEMORY_SCOPE_AGENT);
    __hip_atomic_store(&fw[4 * tid + 3], 0ull, __ATOMIC_RELAXED, __HIP_MEMORY_SCOPE_AGENT);
}

extern "C" void kernel_launch(void* const* d_in, const int* in_sizes, int n_in,
                              void* d_out, int out_size, void* d_ws, size_t ws_size,
                              hipStream_t stream) {
    const float* y_pred       = (const float*)d_in[0];   // (8,1,512,512) f32
    const int*   point_labels = (const int*)d_in[1];     // (8,20) i32
    const float* point_coords = (const float*)d_in[2];   // (8,20,2) f32
    float*       out          = (float*)d_out;           // scalar f32

    char* w = (char*)d_ws;
    unsigned long long* slots = (unsigned long long*)(w);      // 512 x 8B
    unsigned*           flags = (unsigned*)(w + 4096);         // 512 u32 (8B-aligned)

    pce_kernel<<<NBLOCKS, 256, 0, stream>>>(y_pred, point_labels, point_coords,
                                            slots, flags, out);
}

// Round 13
// 19.680 us; speedup vs baseline: 1.7166x; 1.7166x over previous
//
#include <hip/hip_runtime.h>
#include <math.h>

// B=8, N=20, H=W=512. loss = sum(bce*valid)/cnt where the last point n with
// exp(-d2/(2*5^2)) > 0.1 (<=> d2 < 50*ln10) defines the per-pixel label.
// Single dispatch; flat paired-flag handshake (R8, 19.6us) + unconditional
// strip preload to LDS (kills the coords->bbox->load serial chain) + packed
// 8B {S,C} slots.   [R9 optimum restored: 19.56us]

#define R2_THRESH 115.12925464970229f
#define HW 512
#define NPTS 20
#define NBLOCKS 512
#define MAGIC 0x5F3C9A17u
#define MAGIC2 0x5F3C9A175F3C9A17ull

__global__ __launch_bounds__(256)
void pce_kernel(const float* __restrict__ y_pred,
                const int* __restrict__ point_labels,
                const float* __restrict__ point_coords,
                unsigned long long* __restrict__ slots, // [512] packed {C:hi32,S:lo32}
                unsigned* __restrict__ flags,           // [512]; != MAGIC on entry, cleared on exit
                float* __restrict__ out) {
    const int bid  = blockIdx.x;
    const int b    = bid >> 6;
    const int y0   = (bid & 63) * 8;
    const int tid  = threadIdx.x;
    const int r    = tid >> 5;               // 8 rows, 32 lanes each
    const int lane = tid & 31;

    __shared__ float s_strip[8][HW];         // 16 KB
    __shared__ float s_xc[8][NPTS], s_lim[8][NPTS], s_lab[8][NPTS];

    // ---- issue strip loads FIRST (independent of coords; col = lane*4 + j*128) ----
    const float4* grow = (const float4*)(y_pred + (size_t)b * HW * HW + (size_t)(y0 + r) * HW);
    float4 v0 = grow[lane];
    float4 v1 = grow[lane + 32];
    float4 v2 = grow[lane + 64];
    float4 v3 = grow[lane + 96];

    // ---- coords / point tables / bbox (overlaps the strip loads) ----
    float xlo = INFINITY, xhi = -INFINITY;
    if (lane < NPTS) {
        float2 cc = ((const float2*)point_coords)[b * NPTS + lane];
        float yc  = cc.x * (float)HW;
        float xc  = cc.y * (float)HW;
        float dy  = (float)(y0 + r) - yc;
        float lim = R2_THRESH - dy * dy;      // lim<=0 -> dx*dx<lim never true
        s_xc[r][lane]  = xc;
        s_lim[r][lane] = lim;
        s_lab[r][lane] = (float)point_labels[b * NPTS + lane];
        if (lim > 0.0f) {
            float s = sqrtf(lim);
            xlo = xc - s;
            xhi = xc + s;
        }
    }
    #pragma unroll
    for (int off = 16; off > 0; off >>= 1) {
        xlo = fminf(xlo, __shfl_xor(xlo, off, 32));
        xhi = fmaxf(xhi, __shfl_xor(xhi, off, 32));
    }
    const int x0 = (int)fminf(fmaxf(floorf(xlo), 0.0f), 512.0f);
    const int x1 = (int)fminf(fmaxf(ceilf(xhi), -1.0f), 511.0f);   // empty -> x0 > x1

    // ---- strip -> LDS (4-way bank aliasing only) ----
    {
        float4* dst = (float4*)&s_strip[r][0];
        dst[lane]      = v0;
        dst[lane + 32] = v1;
        dst[lane + 64] = v2;
        dst[lane + 96] = v3;
    }
    __syncthreads();

    // ---- pixel loop: reads hit LDS, no global latency on this path ----
    float sum = 0.0f, cnt = 0.0f;
    for (int px = x0 + lane; px <= x1; px += 32) {
        float l = s_strip[r][px];
        const float fx = (float)px;
        float lab = 0.0f;
        bool  valid = false;
        #pragma unroll
        for (int k = 0; k < NPTS; ++k) {
            float dx = fx - s_xc[r][k];
            if (dx * dx < s_lim[r][k]) { lab = s_lab[r][k]; valid = true; }  // last k wins
        }
        if (valid) {
            sum += fmaxf(l, 0.0f) - l * lab + log1pf(expf(-fabsf(l)));
            cnt += 1.0f;
        }
    }

    // ---- block reduction ----
    #pragma unroll
    for (int off = 32; off > 0; off >>= 1) {
        sum += __shfl_down(sum, off, 64);
        cnt += __shfl_down(cnt, off, 64);
    }
    __shared__ float rs[4], rc[4];
    if ((tid & 63) == 0) { rs[tid >> 6] = sum; rc[tid >> 6] = cnt; }
    __syncthreads();
    if (tid == 0) {
        float S = rs[0] + rs[1] + rs[2] + rs[3];
        float C = rc[0] + rc[1] + rc[2] + rc[3];
        unsigned long long w = ((unsigned long long)__float_as_uint(C) << 32)
                             | (unsigned long long)__float_as_uint(S);
        __hip_atomic_store(&slots[bid], w, __ATOMIC_RELAXED, __HIP_MEMORY_SCOPE_AGENT);
        __hip_atomic_store(&flags[bid], MAGIC, __ATOMIC_RELEASE, __HIP_MEMORY_SCOPE_AGENT);
    }
    if (bid != 0) return;

    // ---- block 0: thread t polls blocks {2t,2t+1} as one 8B acquire load ----
    {
        unsigned long long f = 0;
        unsigned long long* fp = (unsigned long long*)&flags[2 * tid];
        do {
            f = __hip_atomic_load(fp, __ATOMIC_ACQUIRE, __HIP_MEMORY_SCOPE_AGENT);
            if (f != MAGIC2) __builtin_amdgcn_s_sleep(1);
        } while (f != MAGIC2);
    }

    // ---- finalize: fixed-order reduction of 512 packed slots ----
    {
        unsigned long long w0 = __hip_atomic_load(&slots[2 * tid + 0], __ATOMIC_RELAXED, __HIP_MEMORY_SCOPE_AGENT);
        unsigned long long w1 = __hip_atomic_load(&slots[2 * tid + 1], __ATOMIC_RELAXED, __HIP_MEMORY_SCOPE_AGENT);
        float S = __uint_as_float((unsigned)(w0 & 0xffffffffull))
                + __uint_as_float((unsigned)(w1 & 0xffffffffull));
        float C = __uint_as_float((unsigned)(w0 >> 32))
                + __uint_as_float((unsigned)(w1 >> 32));
        #pragma unroll
        for (int off = 32; off > 0; off >>= 1) {
            S += __shfl_down(S, off, 64);
            C += __shfl_down(C, off, 64);
        }
        if ((tid & 63) == 0) { rs[tid >> 6] = S; rc[tid >> 6] = C; }
        __syncthreads();
        if (tid == 0) {
            float SS = rs[0] + rs[1] + rs[2] + rs[3];
            float CC = rc[0] + rc[1] + rc[2] + rc[3];
            out[0] = (CC > 0.0f) ? (SS / CC) : 0.0f;
        }
        // clear my two flags for the next replay (my reads are done)
        __hip_atomic_store(&flags[2 * tid + 0], 0u, __ATOMIC_RELAXED, __HIP_MEMORY_SCOPE_AGENT);
        __hip_atomic_store(&flags[2 * tid + 1], 0u, __ATOMIC_RELAXED, __HIP_MEMORY_SCOPE_AGENT);
    }
}

extern "C" void kernel_launch(void* const* d_in, const int* in_sizes, int n_in,
                              void* d_out, int out_size, void* d_ws, size_t ws_size,
                              hipStream_t stream) {
    const float* y_pred       = (const float*)d_in[0];   // (8,1,512,512) f32
    const int*   point_labels = (const int*)d_in[1];     // (8,20) i32
    const float* point_coords = (const float*)d_in[2];   // (8,20,2) f32
    float*       out          = (float*)d_out;           // scalar f32

    char* w = (char*)d_ws;
    unsigned long long* slots = (unsigned long long*)(w);          // 512 x 8B
    unsigned*           flags = (unsigned*)(w + 4096);             // 512 u32 (8B-aligned)

    pce_kernel<<<NBLOCKS, 256, 0, stream>>>(y_pred, point_labels, point_coords,
                                            slots, flags, out);
}